// Round 1
// baseline (372.713 us; speedup 1.0000x reference)
//
#include <hip/hip_runtime.h>
#include <math.h>

#define H 128

// One block per graph segment (batch is sorted -> contiguous row ranges).
// 256 threads = 8 groups x 32 lanes. Group processes one row/iter with
// float4 loads (lane l covers features 4l..4l+3). Single pass over x:
// online softmax (running m, d, rescaled att accumulator) fused with
// sum/max pooling. Then 8-way merge in LDS and fused combine matmul.
__global__ __launch_bounds__(256, 4)
void pool_kernel(const float* __restrict__ x,
                 const int* __restrict__ batch,
                 const float* __restrict__ gate_w,
                 const float* __restrict__ gate_b,
                 const float* __restrict__ combine_w,
                 const float* __restrict__ combine_b,
                 float* __restrict__ out,
                 int N)
{
    const int g    = blockIdx.x;
    const int t    = threadIdx.x;
    const int grp  = t >> 5;   // 0..7
    const int lane = t & 31;   // feature block 4*lane

    __shared__ int   s_range[2];
    __shared__ float s_att[8][H];
    __shared__ float s_sum[8][H];
    __shared__ float s_mx[8][H];
    __shared__ float s_m[8], s_d[8];
    __shared__ float s_comb[3 * H];
    __shared__ float s_part[H];

    // --- segment bounds via binary search (batch sorted ascending) ---
    if (t < 2) {
        int target = g + t;
        int lo = 0, hi = N;
        while (lo < hi) {
            int mid = (lo + hi) >> 1;
            if (batch[mid] < target) lo = mid + 1; else hi = mid;
        }
        s_range[t] = lo;
    }
    __syncthreads();
    const int start = s_range[0];
    const int end   = s_range[1];
    const int cnt   = end - start;

    // per-lane gate weights (features 4*lane..4*lane+3)
    const float4 gw = ((const float4*)gate_w)[lane];
    const float  gb = gate_b[0];

    float  m = -INFINITY, d = 0.0f;
    float4 att = make_float4(0.f, 0.f, 0.f, 0.f);
    float4 sum = make_float4(0.f, 0.f, 0.f, 0.f);
    float4 mx  = make_float4(-INFINITY, -INFINITY, -INFINITY, -INFINITY);

    const float4* xv = (const float4*)x;  // row r, lane l -> xv[r*32 + l]

    int   r    = start + grp;
    bool  curv = (r < end);
    float4 cur = make_float4(0.f, 0.f, 0.f, 0.f);
    if (curv) cur = xv[(size_t)r * 32 + lane];

    while (curv) {
        // software prefetch next row for this group (2 loads in flight/wave)
        int    rn   = r + 8;
        bool   nxtv = (rn < end);
        float4 nxt  = make_float4(0.f, 0.f, 0.f, 0.f);
        if (nxtv) nxt = xv[(size_t)rn * 32 + lane];

        // gate score: dot(x_row, gate_w) reduced across the 32-lane group
        float p = cur.x * gw.x + cur.y * gw.y + cur.z * gw.z + cur.w * gw.w;
        p += __shfl_xor(p, 1);
        p += __shfl_xor(p, 2);
        p += __shfl_xor(p, 4);
        p += __shfl_xor(p, 8);
        p += __shfl_xor(p, 16);
        float gate = p + gb;

        // online softmax update
        float nm = fmaxf(m, gate);
        float sc = __expf(m - nm);      // m=-inf first row -> sc=0
        float e  = __expf(gate - nm);
        m = nm;
        d = d * sc + e;
        att.x = att.x * sc + e * cur.x;
        att.y = att.y * sc + e * cur.y;
        att.z = att.z * sc + e * cur.z;
        att.w = att.w * sc + e * cur.w;

        // mean/max pooling accumulators
        sum.x += cur.x; sum.y += cur.y; sum.z += cur.z; sum.w += cur.w;
        mx.x = fmaxf(mx.x, cur.x);
        mx.y = fmaxf(mx.y, cur.y);
        mx.z = fmaxf(mx.z, cur.z);
        mx.w = fmaxf(mx.w, cur.w);

        r = rn; cur = nxt; curv = nxtv;
    }

    // --- stash per-group partials in LDS ---
    ((float4*)s_att[grp])[lane] = att;
    ((float4*)s_sum[grp])[lane] = sum;
    ((float4*)s_mx[grp])[lane]  = mx;
    if (lane == 0) { s_m[grp] = m; s_d[grp] = d; }
    __syncthreads();

    // --- merge 8 groups; build combined = [att, mean, max] ---
    if (t < H) {
        const int f = t;
        float M = -INFINITY;
        #pragma unroll
        for (int k = 0; k < 8; k++) M = fmaxf(M, s_m[k]);

        float D = 0.f, attf = 0.f, sm = 0.f, mxf = -INFINITY;
        #pragma unroll
        for (int k = 0; k < 8; k++) {
            float w = __expf(s_m[k] - M);   // m=-inf group -> w=0 (cnt>0 case)
            D    += w * s_d[k];
            attf += w * s_att[k][f];
            sm   += s_sum[k][f];
            mxf   = fmaxf(mxf, s_mx[k][f]);
        }

        float o_att, o_mean, o_mx;
        if (cnt > 0) {
            o_att  = attf / fmaxf(D, 1e-16f);
            o_mean = sm / (float)cnt;
            o_mx   = mxf;
        } else {
            o_att = 0.f; o_mean = 0.f; o_mx = 0.f;  // matches isfinite guards
        }
        s_comb[f]         = o_att;
        s_comb[H + f]     = o_mean;
        s_comb[2 * H + f] = o_mx;
    }
    __syncthreads();

    // --- fused combine matmul: out[g,:] = combined @ W + b  (W: [384,128]) ---
    {
        const int j    = t & (H - 1);   // output column
        const int half = t >> 7;        // 0 or 1: split k-range 2-way
        const int k0   = half * 192;
        float acc = 0.f;
        #pragma unroll 8
        for (int k = k0; k < k0 + 192; k++)
            acc += s_comb[k] * combine_w[k * H + j];
        if (half == 0) s_part[j] = acc;
        __syncthreads();
        if (half == 1)
            out[(size_t)g * H + j] = acc + s_part[j] + combine_b[j];
    }
}

extern "C" void kernel_launch(void* const* d_in, const int* in_sizes, int n_in,
                              void* d_out, int out_size, void* d_ws, size_t ws_size,
                              hipStream_t stream) {
    const float* x         = (const float*)d_in[0];
    const int*   batch     = (const int*)d_in[1];
    const float* gate_w    = (const float*)d_in[2];
    const float* gate_b    = (const float*)d_in[3];
    const float* combine_w = (const float*)d_in[4];
    const float* combine_b = (const float*)d_in[5];
    // d_in[6] = num_graphs scalar (device); G derived from out_size instead.
    float* out = (float*)d_out;

    const int N = in_sizes[0] / H;
    const int G = out_size / H;

    pool_kernel<<<G, 256, 0, stream>>>(x, batch, gate_w, gate_b,
                                       combine_w, combine_b, out, N);
}